// Round 15
// baseline (141.189 us; speedup 1.0000x reference)
//
#include <hip/hip_runtime.h>
#include <hip/hip_bf16.h>
#include <stdint.h>
#include <math.h>

#define HIDDEN 1024
#define NHEADS 16
#define HDIM   64
#define BSZ    4
#define QLEN   1024
#define KVLEN  2048

typedef __bf16 bf16_t;
typedef __bf16 bf16x8 __attribute__((ext_vector_type(8)));
typedef __bf16 bf16x4 __attribute__((ext_vector_type(4)));
typedef float  f32x4  __attribute__((ext_vector_type(4)));

// fixed-max softmax: p = exp2( s_raw*C_SCALE + madd ).
#define C_SCALE 0.18033688f     /* 0.125 * log2(e) */
#define C_FMADD (-43.2808512f)  /* -30 * log2(e) */

#define GLOAD16(g, l) \
    __builtin_amdgcn_global_load_lds((const __attribute__((address_space(1))) void*)(g), \
                                     (__attribute__((address_space(3))) void*)(l), 16, 0, 0)

__device__ __forceinline__ float clamp50(float v) {
    return fminf(fmaxf(v, -50.f), 50.f);
}

// ---------------------------------------------------------------------------
// Converts the 4 weights (fp32 -> bf16) AND the mask (dtype auto-detect ->
// additive exp2-domain constant). q/kv conversion is fused into proj staging.
// ---------------------------------------------------------------------------
#define NW4  ((HIDDEN * HIDDEN) / 4)        /* 262144 */
#define NWCVT (4 * NW4 / 256)               /* 4096 blocks */

__global__ void cvt_w_mask_kernel(const float* __restrict__ W0, const float* __restrict__ W1,
                                  const float* __restrict__ W2, const float* __restrict__ W3,
                                  bf16_t* __restrict__ w_bf,
                                  const void* __restrict__ msk, float* __restrict__ maskadd) {
    if (blockIdx.x >= NWCVT) {
        __shared__ int s_float, s_multi;
        const int t = threadIdx.x;
        if (t == 0) { s_float = 0; s_multi = 0; }
        __syncthreads();
        const uint32_t* w = (const uint32_t*)msk;
        int cf = 0, cm = 0;
        for (int i = t; i < 2048; i += 256) {
            uint32_t v = w[i];
            if (v == 0x3F800000u) cf++;
            else if (v & 0xFFFFFF00u) cm++;
        }
        if (cf) atomicAdd(&s_float, cf);
        if (cm) atomicAdd(&s_multi, cm);
        __syncthreads();
        const int mode = (s_float > 0) ? 2 : ((s_multi > 0) ? 0 : 1);
        const int base = (blockIdx.x - NWCVT) * 2048;
        for (int i = base + t; i < base + 2048; i += 256) {
            bool m;
            if (mode == 2)      m = ((const float*)msk)[i] != 0.0f;
            else if (mode == 1) m = ((const int*)msk)[i] != 0;
            else                m = ((const unsigned char*)msk)[i] != 0;
            maskadd[i] = m ? (-100000.0f + C_FMADD) : C_FMADD;
        }
        return;
    }
    const int i = blockIdx.x * blockDim.x + threadIdx.x;
    const int ws = i >> 18, off = i & (NW4 - 1);
    const float* W = (ws == 0) ? W0 : (ws == 1) ? W1 : (ws == 2) ? W2 : W3;
    const float4 v = ((const float4*)W)[off];
    bf16x4 o;
    o[0] = (bf16_t)clamp50(v.x); o[1] = (bf16_t)clamp50(v.y);
    o[2] = (bf16_t)clamp50(v.z); o[3] = (bf16_t)clamp50(v.w);
    ((bf16x4*)w_bf)[(size_t)ws * NW4 + off] = o;
}

// ---------------------------------------------------------------------------
// Projection GEMM v5 = v4 + sched_barrier(0) pin after prefetch issue.
// 128x128 tile, BK=64, 8 waves (2m x 4n), LDS 48 KB (A single 16K + B 2x16K,
// 3 blocks/CU). A fp32 reg-staged (fused clamp+cvt). The sched_barrier
// prevents the compiler from SINKING the A-loads to their use point (R14
// evidence: VGPR_Count=40 -> pipe registers not kept live -> every iter
// stalled on raw load latency at the barrier).
// ---------------------------------------------------------------------------
#define AOFF  0          /* A single buffer, 16 KB */
#define BOFF  16384      /* B buffers at 16K and 32K */
#define BBUF  16384

#define PROJ_CVT_WRITE_A(wr0, wr1) \
    _Pragma("unroll") for (int i_ = 0; i_ < 2; ++i_) { \
        bf16x8 o_; \
        o_[0] = (bf16_t)clamp50(wr0[i_].x); o_[1] = (bf16_t)clamp50(wr0[i_].y); \
        o_[2] = (bf16_t)clamp50(wr0[i_].z); o_[3] = (bf16_t)clamp50(wr0[i_].w); \
        o_[4] = (bf16_t)clamp50(wr1[i_].x); o_[5] = (bf16_t)clamp50(wr1[i_].y); \
        o_[6] = (bf16_t)clamp50(wr1[i_].z); o_[7] = (bf16_t)clamp50(wr1[i_].w); \
        *(bf16x8*)(Ls + AOFF + i_ * 8192 + wave * 1024 + lane * 16) = o_; \
    }

__device__ __forceinline__ void proj_core5(const char* __restrict__ Ab,   // fp32
                                           const char* __restrict__ Bb,   // bf16
                                           char* Ls, f32x4 (&acc)[4][2],
                                           int wave, int lane, int wm, int wn)
{
    const int srcsw = ((lane & 7) ^ (lane >> 3)) << 4;
    const int rowl = lane >> 3;
    const int ql = lane & 15;

    float4 e0[2], e1[2];

    // ---- prologue: A0 -> regs, B0 glds -> buf0, write A0, barrier
#pragma unroll
    for (int i = 0; i < 2; ++i) {
        const int row = i * 64 + wave * 8 + rowl;
        const float4* p = (const float4*)(Ab + (size_t)row * (HIDDEN * 4) + (srcsw << 1));
        e0[i] = p[0]; e1[i] = p[1];
        GLOAD16(Bb + (size_t)row * (HIDDEN * 2) + srcsw,
                Ls + BOFF + i * 8192 + wave * 1024);
    }
    PROJ_CVT_WRITE_A(e0, e1)
    __syncthreads();

    for (int kt = 0; kt < HIDDEN / 64; ++kt) {
        const int cur = kt & 1;
        // ---- issue next tile early; PIN the issue point so the compiler
        //      cannot sink these loads to their use (the ds_write below).
        if (kt < HIDDEN / 64 - 1) {
#pragma unroll
            for (int i = 0; i < 2; ++i) {
                const int row = i * 64 + wave * 8 + rowl;
                const float4* p = (const float4*)(Ab + (size_t)row * (HIDDEN * 4)
                                                  + (kt + 1) * 256 + (srcsw << 1));
                e0[i] = p[0]; e1[i] = p[1];
                GLOAD16(Bb + (size_t)row * (HIDDEN * 2) + (kt + 1) * 128 + srcsw,
                        Ls + BOFF + (cur ^ 1) * BBUF + i * 8192 + wave * 1024);
            }
            __builtin_amdgcn_sched_barrier(0);   // loads issued HERE, before MFMA
        }
        // ---- compute tile k: A from single buffer, B from buf[cur]
        const char* Abase = Ls + AOFF;
        const char* Bbase = Ls + BOFF + cur * BBUF;
#pragma unroll
        for (int kc = 0; kc < 2; ++kc) {
            const int kbyte = kc * 64 + ((lane >> 4) << 4);
            bf16x8 af[4], bfr[2];
#pragma unroll
            for (int f2 = 0; f2 < 4; ++f2) {
                const int arow = wm * 64 + f2 * 16 + ql;
                af[f2] = *(const bf16x8*)(Abase + arow * 128 + (kbyte ^ ((arow & 7) << 4)));
            }
#pragma unroll
            for (int f2 = 0; f2 < 2; ++f2) {
                const int brow = wn * 32 + f2 * 16 + ql;
                bfr[f2] = *(const bf16x8*)(Bbase + brow * 128 + (kbyte ^ ((brow & 7) << 4)));
            }
#pragma unroll
            for (int mf = 0; mf < 4; ++mf)
#pragma unroll
                for (int nf = 0; nf < 2; ++nf)
                    acc[mf][nf] = __builtin_amdgcn_mfma_f32_16x16x32_bf16(af[mf], bfr[nf], acc[mf][nf], 0, 0, 0);
        }
        __syncthreads();   // all waves done reading A(k); B glds drained
        // ---- write A(k+1) into the single A buffer (regs arrived during MFMA)
        if (kt < HIDDEN / 64 - 1) {
            PROJ_CVT_WRITE_A(e0, e1)
            __syncthreads();   // lgkm-only: A writes visible before next compute
        }
    }
}

// EPI epilogue: bf16 out in per-head layout [(b*16+h)][s][d], seqlen 1<<slog
template <int NF>
__device__ __forceinline__ void epi_head(f32x4 (&acc)[4][NF], const float* bias,
                                         bf16_t* out, int m0, int n0, int slog,
                                         int wm, int wn, int lane)
{
#pragma unroll
    for (int mf = 0; mf < 4; ++mf) {
#pragma unroll
        for (int nf = 0; nf < NF; ++nf) {
            const int gn = n0 + wn * (NF * 16) + nf * 16 + (lane & 15);
            const float bv = bias[gn];
#pragma unroll
            for (int r = 0; r < 4; ++r) {
                const int gm = m0 + wm * 64 + mf * 16 + ((lane >> 4) << 2) + r;
                const float v = clamp50(acc[mf][nf][r] + bv);
                const int b = gm >> slog;
                const int s = gm & ((1 << slog) - 1);
                const int h = gn >> 6, d = gn & 63;
                out[((((size_t)(b * NHEADS + h)) << slog) + s) * HDIM + d] = (bf16_t)v;
            }
        }
    }
}

// ---------------------------------------------------------------------------
// MERGED projection GEMM v5, fused A-conversion. Grid 1280, 512 thr (8 waves).
// Bijective XCD swizzle lid = (bid&7)*160 + (bid>>3): 8 consecutive lids share
// an A m-panel on one XCD -> fp32 panel L2-resident after first fetch.
// ---------------------------------------------------------------------------
__global__ __launch_bounds__(512)
void gemm_proj_all(const float* __restrict__ qf32, const float* __restrict__ kvf32,
                   const bf16_t* __restrict__ w_bf,
                   const float* __restrict__ bq, const float* __restrict__ bk,
                   const float* __restrict__ bv,
                   bf16_t* __restrict__ qh, bf16_t* __restrict__ kh,
                   bf16_t* __restrict__ vt)
{
    __shared__ __align__(16) char Smem[49152];   // 48 KB: A 16K + B 2x16K

    const int bid = blockIdx.x;
    const int lid = (bid & 7) * 160 + (bid >> 3);

    int seg, j;
    if (lid < 256)      { seg = 0; j = lid; }
    else if (lid < 768) { seg = 1; j = lid - 256; }
    else                { seg = 2; j = lid - 768; }
    const int m0 = (j >> 3) * 128;
    const int n0 = (j & 7) * 128;
    const float*  A    = (seg == 0) ? qf32 : kvf32;
    const bf16_t* B    = w_bf + (size_t)seg * (HIDDEN * HIDDEN);   // Wq, Wk, Wv
    const float*  bias = (seg == 0) ? bq : (seg == 1) ? bk : bv;

    const int t = threadIdx.x;
    const int wave = t >> 6, lane = t & 63;
    const int wm = wave >> 2, wn = wave & 3;

    f32x4 acc[4][2] = {};
    proj_core5((const char*)A + (size_t)m0 * (HIDDEN * 4),
               (const char*)B + (size_t)n0 * (HIDDEN * 2),
               (char*)Smem, acc, wave, lane, wm, wn);

    if (seg == 0) {
        epi_head<2>(acc, bias, qh, m0, n0, 10, wm, wn, lane);
        return;
    }
    if (seg == 1) {
        epi_head<2>(acc, bias, kh, m0, n0, 11, wm, wn, lane);
        return;
    }

    // V: transpose epilogue via LDS (reuse Smem), 2 phases of 64 s-rows.
    bf16_t* Cls = (bf16_t*)Smem;         // [64][130]
    const int dl = t >> 2;               // 0..127
    const int sh = (t & 3) << 4;         // 0,16,32,48
    const int gn = n0 + dl;
    const int h = gn >> 6, d = gn & 63;
    const int bb = m0 >> 11;
    bf16_t* dst = vt + ((size_t)((bb * NHEADS + h) * HDIM + d)) * KVLEN
                + (m0 & (KVLEN - 1)) + sh;
    __syncthreads();
#pragma unroll
    for (int ph = 0; ph < 2; ++ph) {
        if (wm == ph) {
#pragma unroll
            for (int mf = 0; mf < 4; ++mf) {
#pragma unroll
                for (int nf = 0; nf < 2; ++nf) {
                    const int dcol = wn * 32 + nf * 16 + (lane & 15);
                    const float bv2 = bias[n0 + dcol];
#pragma unroll
                    for (int r = 0; r < 4; ++r) {
                        const int srow = mf * 16 + ((lane >> 4) << 2) + r;
                        Cls[srow * 130 + dcol] = (bf16_t)clamp50(acc[mf][nf][r] + bv2);
                    }
                }
            }
        }
        __syncthreads();
#pragma unroll
        for (int j0 = 0; j0 < 16; j0 += 8) {
            bf16x8 v;
#pragma unroll
            for (int jj = 0; jj < 8; ++jj) v[jj] = Cls[(sh + j0 + jj) * 130 + dl];
            *(bf16x8*)(dst + ph * 64 + j0) = v;
        }
        __syncthreads();
    }
}

// ---------------------------------------------------------------------------
// 8-WAVE all-bf16 GEMM core (output projection), 128xNT, dbuf glds.
// ---------------------------------------------------------------------------
template <int NT>
__device__ __forceinline__ void stage_tile8(const char* __restrict__ Ab,
                                            const char* __restrict__ Bb,
                                            char* base, int kt, int wave, int rowl, int srcsw)
{
#pragma unroll
    for (int i = 0; i < 2; ++i) {
        const int row = i * 64 + wave * 8 + rowl;
        GLOAD16(Ab + (size_t)row * (HIDDEN * 2) + kt * 128 + srcsw,
                base + i * 8192 + wave * 1024);
    }
#pragma unroll
    for (int i = 0; i < NT / 64; ++i) {
        const int row = i * 64 + wave * 8 + rowl;
        GLOAD16(Bb + (size_t)row * (HIDDEN * 2) + kt * 128 + srcsw,
                base + 16384 + i * 8192 + wave * 1024);
    }
}

template <int NT>
__device__ __forceinline__ void gemm_core_db8(const char* __restrict__ Ab,
                                              const char* __restrict__ Bb,
                                              char* Ls,
                                              f32x4 (&acc)[4][NT / 64],
                                              int wave, int lane, int wm, int wn)
{
    constexpr int NFB = NT / 64;
    constexpr int BUF = (128 + NT) * 128;
    const int srcsw = ((lane & 7) ^ (lane >> 3)) << 4;
    const int rowl = lane >> 3;
    const int ql = lane & 15;

    stage_tile8<NT>(Ab, Bb, Ls, 0, wave, rowl, srcsw);
    __syncthreads();

    for (int kt = 0; kt < HIDDEN / 64; ++kt) {
        const int cur = kt & 1;
        if (kt < HIDDEN / 64 - 1)
            stage_tile8<NT>(Ab, Bb, Ls + (cur ^ 1) * BUF, kt + 1, wave, rowl, srcsw);
        const char* Abase = Ls + cur * BUF;
        const char* Bbase = Abase + 16384;
#pragma unroll
        for (int kc = 0; kc < 2; ++kc) {
            const int kbyte = kc * 64 + ((lane >> 4) << 4);
            bf16x8 af[4], bfr[NFB];
#pragma unroll
            for (int f2 = 0; f2 < 4; ++f2) {
                const int arow = wm * 64 + f2 * 16 + ql;
                af[f2] = *(const bf16x8*)(Abase + arow * 128 + (kbyte ^ ((arow & 7) << 4)));
            }
#pragma unroll
            for (int f2 = 0; f2 < NFB; ++f2) {
                const int brow = wn * (NT / 4) + f2 * 16 + ql;
                bfr[f2] = *(const bf16x8*)(Bbase + brow * 128 + (kbyte ^ ((brow & 7) << 4)));
            }
#pragma unroll
            for (int mf = 0; mf < 4; ++mf)
#pragma unroll
                for (int nf = 0; nf < NFB; ++nf)
                    acc[mf][nf] = __builtin_amdgcn_mfma_f32_16x16x32_bf16(af[mf], bfr[nf], acc[mf][nf], 0, 0, 0);
        }
        __syncthreads();
    }
}

// ---------------------------------------------------------------------------
// Output-projection GEMM (fp32 out [M][1024]), 128x64 tiles, 8 waves,
// dbuf core, 1D grid 512 with panel-per-XCD swizzle.
// ---------------------------------------------------------------------------
__global__ __launch_bounds__(512)
void gemm_out_kernel(const bf16_t* __restrict__ A, const bf16_t* __restrict__ B,
                     const float* __restrict__ bias, float* __restrict__ out)
{
    constexpr int NT = 64;
    __shared__ __align__(16) bf16_t Smem[2 * (128 + NT) * 64];   // 48 KB

    const int bid = blockIdx.x;
    const int lid = (bid & 7) * 64 + (bid >> 3);   // 512 = 8 x 64, bijective
    const int m0 = (lid >> 4) * 128;
    const int n0 = (lid & 15) * NT;
    const int t = threadIdx.x;
    const int wave = t >> 6, lane = t & 63;
    const int wm = wave >> 2, wn = wave & 3;

    f32x4 acc[4][1] = {};
    gemm_core_db8<NT>((const char*)A + (size_t)m0 * (HIDDEN * 2),
                      (const char*)B + (size_t)n0 * (HIDDEN * 2),
                      (char*)Smem, acc, wave, lane, wm, wn);

#pragma unroll
    for (int mf = 0; mf < 4; ++mf) {
        const int gn = n0 + wn * 16 + (lane & 15);
        const float bv = bias[gn];
#pragma unroll
        for (int r = 0; r < 4; ++r) {
            const int gm = m0 + wm * 64 + mf * 16 + ((lane >> 4) << 2) + r;
            out[(size_t)gm * HIDDEN + gn] = clamp50(acc[mf][0][r] + bv);
        }
    }
}

// ---------------------------------------------------------------------------
// Flash attention v3: fixed-max softmax, swapped QK^T (P in registers),
// key-half split across wave pairs, 8 waves / 512 threads, XCD-grouped.
// ---------------------------------------------------------------------------
__global__ __launch_bounds__(512)
void attn_fwd_kernel(const bf16_t* __restrict__ Qh, const bf16_t* __restrict__ Kh,
                     const bf16_t* __restrict__ Vt, const float* __restrict__ maskadd,
                     bf16_t* __restrict__ aout)
{
    __shared__ __align__(16) bf16_t Kls[2][64 * 64];   // 16 KB
    __shared__ __align__(16) bf16_t Vls[2][64 * 64];   // 16 KB
    __shared__ __align__(16) float Cbuf[4][32 * 64];   // 32 KB combine
    __shared__ float Lbuf[4][2][16];

    const int f = blockIdx.x;
    const int o = (f & 7) * 64 + (f >> 3);
    const int qt = o & 7;
    const int bh = o >> 3;
    const int b = bh >> 4, h = bh & 15;
    const int t = threadIdx.x, wave = t >> 6, lane = t & 63;
    const int wq = wave & 3;
    const int wg = wave >> 2;
    const int g = lane >> 4, ql = lane & 15;

    const int qbase = qt * 128 + wq * 32;
    bf16x8 qf[2][2];
#pragma unroll
    for (int qq = 0; qq < 2; ++qq) {
        const bf16_t* qp = Qh + ((size_t)bh * QLEN + qbase + qq * 16 + ql) * HDIM + (g << 3);
        qf[qq][0] = *(const bf16x8*)qp;
        qf[qq][1] = *(const bf16x8*)(qp + 32);
    }

    f32x4 oacc[2][4] = {};
    float lsum[2] = {0.f, 0.f};

    const int srcsw = ((lane & 7) ^ (lane >> 3)) << 4;
    const int R = wave * 8 + (lane >> 3);
    const int kap = 32 * (R >> 5) + 8 * ((R >> 2) & 3) + 4 * ((R >> 4) & 1) + (R & 3);

    const char* Kb = (const char*)(Kh + (size_t)bh * KVLEN * HDIM);
    const char* Vb = (const char*)(Vt + (size_t)bh * HDIM * KVLEN);
    const float* mrow = maskadd + b * KVLEN + wg * 32 + g * 8;
    const int kb0 = g << 4;
    const int vcol = wg * 64 + kb0;

    GLOAD16(Kb + (size_t)kap * 128 + srcsw, (char*)&Kls[0][0] + wave * 1024);
    GLOAD16(Vb + (size_t)R * (KVLEN * 2) + srcsw, (char*)&Vls[0][0] + wave * 1024);
    f32x4 madd_c[2], madd_n[2];
    madd_c[0] = *(const f32x4*)(mrow);
    madd_c[1] = *(const f32x4*)(mrow + 4);
    __syncthreads();

    for (int kt = 0; kt < KVLEN / 64; ++kt) {
        const int cur = kt & 1;
        if (kt < KVLEN / 64 - 1) {
            const size_t ko = (size_t)(kt + 1) * 8192;
            GLOAD16(Kb + ko + (size_t)kap * 128 + srcsw,
                    (char*)&Kls[cur ^ 1][0] + wave * 1024);
            GLOAD16(Vb + (size_t)R * (KVLEN * 2) + (size_t)(kt + 1) * 128 + srcsw,
                    (char*)&Vls[cur ^ 1][0] + wave * 1024);
            madd_n[0] = *(const f32x4*)(mrow + (kt + 1) * 64);
            madd_n[1] = *(const f32x4*)(mrow + (kt + 1) * 64 + 4);
        }
        const char* Kc = (const char*)&Kls[cur][0];
        const char* Vc = (const char*)&Vls[cur][0];

        // ---- S^T = K Q^T over this wave's 32-key half
        f32x4 sacc[2][2] = {};
        __builtin_amdgcn_s_setprio(1);
#pragma unroll
        for (int kb = 0; kb < 2; ++kb) {
            const int key = wg * 32 + kb * 16 + ql;
            const int rowoff = key * 128;
            const int sw = (key & 7) << 4;
            const bf16x8 kf0 = *(const bf16x8*)(Kc + rowoff + ((kb0)      ^ sw));
            const bf16x8 kf1 = *(const bf16x8*)(Kc + rowoff + ((kb0 + 64) ^ sw));
#pragma unroll
            for (int qq = 0; qq < 2; ++qq) {
                sacc[qq][kb] = __builtin_amdgcn_mfma_f32_16x16x32_bf16(kf0, qf[qq][0], sacc[qq][kb], 0, 0, 0);
                sacc[qq][kb] = __builtin_amdgcn_mfma_f32_16x16x32_bf16(kf1, qf[qq][1], sacc[qq][kb], 0, 0, 0);
            }
        }
        __builtin_amdgcn_s_setprio(0);

        // ---- softmax weights in-register + pack to PV A-fragment
        bf16x8 pa[2];
#pragma unroll
        for (int qq = 0; qq < 2; ++qq) {
            float pv[2][4];
            float ls = 0.f;
#pragma unroll
            for (int kb = 0; kb < 2; ++kb) {
#pragma unroll
                for (int r = 0; r < 4; ++r) {
                    pv[kb][r] = __builtin_amdgcn_exp2f(
                        __builtin_fmaf(sacc[qq][kb][r], C_SCALE, madd_c[kb][r]));
                    ls += pv[kb][r];
                }
            }
            lsum[qq] += ls;
#pragma unroll
            for (int r = 0; r < 4; ++r) {
                pa[qq][r]     = (bf16_t)pv[0][r];
                pa[qq][4 + r] = (bf16_t)pv[1][r];
            }
        }

        // ---- O += P V over this key half
        __builtin_amdgcn_s_setprio(1);
#pragma unroll
        for (int db = 0; db < 4; ++db) {
            const int vrow = db * 16 + ql;
            const int vsw = (vrow & 7) << 4;
            const bf16x8 vf = *(const bf16x8*)(Vc + vrow * 128 + (vcol ^ vsw));
#pragma unroll
            for (int qq = 0; qq < 2; ++qq)
                oacc[qq][db] = __builtin_amdgcn_mfma_f32_16x16x32_bf16(pa[qq], vf, oacc[qq][db], 0, 0, 0);
        }
        __builtin_amdgcn_s_setprio(0);

        __syncthreads();
#pragma unroll
        for (int kb = 0; kb < 2; ++kb) madd_c[kb] = madd_n[kb];
    }

    // ---- combine key-halves: wg=1 publishes partials, wg=0 merges+stores
#pragma unroll
    for (int qq = 0; qq < 2; ++qq) {
        float l = lsum[qq];
        l += __shfl_xor(l, 16);
        l += __shfl_xor(l, 32);
        lsum[qq] = l;
    }
    const int rbase = g << 2;
    if (wg == 1) {
#pragma unroll
        for (int qq = 0; qq < 2; ++qq) {
#pragma unroll
            for (int db = 0; db < 4; ++db)
#pragma unroll
                for (int r = 0; r < 4; ++r)
                    Cbuf[wq][(qq * 16 + rbase + r) * 64 + db * 16 + ql] = oacc[qq][db][r];
            if (lane < 16) Lbuf[wq][qq][lane] = lsum[qq];
        }
    }
    __syncthreads();
    if (wg == 0) {
#pragma unroll
        for (int qq = 0; qq < 2; ++qq) {
            const float Lq = lsum[qq] + Lbuf[wq][qq][ql];
#pragma unroll
            for (int r = 0; r < 4; ++r) {
                const float Lr = __shfl(Lq, rbase + r);
                const float inv = 1.0f / Lr;
                const int qrow = qbase + qq * 16 + rbase + r;
                bf16_t* orow = aout + ((size_t)(b * QLEN + qrow)) * HIDDEN + h * HDIM;
#pragma unroll
                for (int db = 0; db < 4; ++db) {
                    const float add = Cbuf[wq][(qq * 16 + rbase + r) * 64 + db * 16 + ql];
                    orow[db * 16 + ql] = (bf16_t)((oacc[qq][db][r] + add) * inv);
                }
            }
        }
    }
}

// ---------------------------------------------------------------------------
extern "C" void kernel_launch(void* const* d_in, const int* in_sizes, int n_in,
                              void* d_out, int out_size, void* d_ws, size_t ws_size,
                              hipStream_t stream) {
    (void)in_sizes; (void)n_in; (void)out_size; (void)ws_size;
    const float* q   = (const float*)d_in[0];
    const float* kv  = (const float*)d_in[1];
    const void*  msk = d_in[2];
    const float* Wq  = (const float*)d_in[3];
    const float* bq  = (const float*)d_in[4];
    const float* Wk  = (const float*)d_in[5];
    const float* bk  = (const float*)d_in[6];
    const float* Wv  = (const float*)d_in[7];
    const float* bv  = (const float*)d_in[8];
    const float* Wo  = (const float*)d_in[9];
    const float* bo  = (const float*)d_in[10];

    char* ws = (char*)d_ws;
    const size_t MB = 1024 * 1024;
    float*  maskadd = (float*)ws;                              // 32 KB
    bf16_t* w_bf  = (bf16_t*)(ws + 32 * 1024);                 // 8 MB (4 weights)
    bf16_t* aout  = (bf16_t*)(ws + 32 * 1024 + 8  * MB);       // 8 MB
    bf16_t* qh    = (bf16_t*)(ws + 32 * 1024 + 32 * MB);       // 8 MB
    bf16_t* kh    = (bf16_t*)(ws + 32 * 1024 + 40 * MB);       // 16 MB
    bf16_t* vt    = (bf16_t*)(ws + 32 * 1024 + 56 * MB);       // 16 MB -> end 72 MB

    bf16_t* wo_bf = w_bf + (size_t)3 * HIDDEN * HIDDEN;

    cvt_w_mask_kernel<<<dim3(NWCVT + 4), 256, 0, stream>>>(
        Wq, Wk, Wv, Wo, w_bf, msk, maskadd);

    gemm_proj_all<<<dim3(1280), 512, 0, stream>>>(
        q, kv, w_bf, bq, bk, bv, qh, kh, vt);

    attn_fwd_kernel<<<dim3(512), 512, 0, stream>>>(qh, kh, vt, maskadd, aout);

    gemm_out_kernel<<<dim3(512), 512, 0, stream>>>(aout, wo_bf, bo, (float*)d_out);
}

// Round 16
// 136.085 us; speedup vs baseline: 1.0375x; 1.0375x over previous
//
#include <hip/hip_runtime.h>
#include <hip/hip_bf16.h>
#include <stdint.h>
#include <math.h>

#define HIDDEN 1024
#define NHEADS 16
#define HDIM   64
#define BSZ    4
#define QLEN   1024
#define KVLEN  2048

typedef __bf16 bf16_t;
typedef __bf16 bf16x8 __attribute__((ext_vector_type(8)));
typedef __bf16 bf16x4 __attribute__((ext_vector_type(4)));
typedef float  f32x4  __attribute__((ext_vector_type(4)));

// fixed-max softmax: p = exp2( s_raw*C_SCALE + madd ).
#define C_SCALE 0.18033688f     /* 0.125 * log2(e) */
#define C_FMADD (-43.2808512f)  /* -30 * log2(e) */

#define GLOAD16(g, l) \
    __builtin_amdgcn_global_load_lds((const __attribute__((address_space(1))) void*)(g), \
                                     (__attribute__((address_space(3))) void*)(l), 16, 0, 0)

__device__ __forceinline__ float clamp50(float v) {
    return fminf(fmaxf(v, -50.f), 50.f);
}

// ---------------------------------------------------------------------------
// Converts the 4 weights (fp32 -> bf16) AND the mask (dtype auto-detect ->
// additive exp2-domain constant). q/kv conversion is fused into proj staging.
// ---------------------------------------------------------------------------
#define NW4  ((HIDDEN * HIDDEN) / 4)        /* 262144 */
#define NWCVT (4 * NW4 / 256)               /* 4096 blocks */

__global__ void cvt_w_mask_kernel(const float* __restrict__ W0, const float* __restrict__ W1,
                                  const float* __restrict__ W2, const float* __restrict__ W3,
                                  bf16_t* __restrict__ w_bf,
                                  const void* __restrict__ msk, float* __restrict__ maskadd) {
    if (blockIdx.x >= NWCVT) {
        __shared__ int s_float, s_multi;
        const int t = threadIdx.x;
        if (t == 0) { s_float = 0; s_multi = 0; }
        __syncthreads();
        const uint32_t* w = (const uint32_t*)msk;
        int cf = 0, cm = 0;
        for (int i = t; i < 2048; i += 256) {
            uint32_t v = w[i];
            if (v == 0x3F800000u) cf++;
            else if (v & 0xFFFFFF00u) cm++;
        }
        if (cf) atomicAdd(&s_float, cf);
        if (cm) atomicAdd(&s_multi, cm);
        __syncthreads();
        const int mode = (s_float > 0) ? 2 : ((s_multi > 0) ? 0 : 1);
        const int base = (blockIdx.x - NWCVT) * 2048;
        for (int i = base + t; i < base + 2048; i += 256) {
            bool m;
            if (mode == 2)      m = ((const float*)msk)[i] != 0.0f;
            else if (mode == 1) m = ((const int*)msk)[i] != 0;
            else                m = ((const unsigned char*)msk)[i] != 0;
            maskadd[i] = m ? (-100000.0f + C_FMADD) : C_FMADD;
        }
        return;
    }
    const int i = blockIdx.x * blockDim.x + threadIdx.x;
    const int ws = i >> 18, off = i & (NW4 - 1);
    const float* W = (ws == 0) ? W0 : (ws == 1) ? W1 : (ws == 2) ? W2 : W3;
    const float4 v = ((const float4*)W)[off];
    bf16x4 o;
    o[0] = (bf16_t)clamp50(v.x); o[1] = (bf16_t)clamp50(v.y);
    o[2] = (bf16_t)clamp50(v.z); o[3] = (bf16_t)clamp50(v.w);
    ((bf16x4*)w_bf)[(size_t)ws * NW4 + off] = o;
}

// ---------------------------------------------------------------------------
// Projection GEMM v4: 128x128 tile, BK=64, 8 waves (2m x 4n), per-wave
// output 64x32 (acc[4][2]). LDS 48 KB: A SINGLE buffer 16 KB + B double
// buffer 2 x 16 KB -> 3 blocks/CU (6 waves/SIMD).
// A is fp32 (fused clamp+cvt): loads issued BEFORE compute; ds_write AFTER
// barrier 1 (all waves done reading A(k)); barrier 2 = lgkm visibility.
// B staged via global_load_lds into buf[cur^1], issued pre-compute.
// Source-side swizzle: LDS[row][c] = G[row][c^(row&7)].
// ---------------------------------------------------------------------------
#define AOFF  0          /* A single buffer, 16 KB */
#define BOFF  16384      /* B buffers at 16K and 32K */
#define BBUF  16384

#define PROJ_CVT_WRITE_A(wr0, wr1) \
    _Pragma("unroll") for (int i_ = 0; i_ < 2; ++i_) { \
        bf16x8 o_; \
        o_[0] = (bf16_t)clamp50(wr0[i_].x); o_[1] = (bf16_t)clamp50(wr0[i_].y); \
        o_[2] = (bf16_t)clamp50(wr0[i_].z); o_[3] = (bf16_t)clamp50(wr0[i_].w); \
        o_[4] = (bf16_t)clamp50(wr1[i_].x); o_[5] = (bf16_t)clamp50(wr1[i_].y); \
        o_[6] = (bf16_t)clamp50(wr1[i_].z); o_[7] = (bf16_t)clamp50(wr1[i_].w); \
        *(bf16x8*)(Ls + AOFF + i_ * 8192 + wave * 1024 + lane * 16) = o_; \
    }

__device__ __forceinline__ void proj_core4(const char* __restrict__ Ab,   // fp32
                                           const char* __restrict__ Bb,   // bf16
                                           char* Ls, f32x4 (&acc)[4][2],
                                           int wave, int lane, int wm, int wn)
{
    const int srcsw = ((lane & 7) ^ (lane >> 3)) << 4;
    const int rowl = lane >> 3;
    const int ql = lane & 15;

    float4 e0[2], e1[2];

    // ---- prologue: A0 -> regs, B0 glds -> buf0, write A0, barrier
#pragma unroll
    for (int i = 0; i < 2; ++i) {
        const int row = i * 64 + wave * 8 + rowl;
        const float4* p = (const float4*)(Ab + (size_t)row * (HIDDEN * 4) + (srcsw << 1));
        e0[i] = p[0]; e1[i] = p[1];
        GLOAD16(Bb + (size_t)row * (HIDDEN * 2) + srcsw,
                Ls + BOFF + i * 8192 + wave * 1024);
    }
    PROJ_CVT_WRITE_A(e0, e1)
    __syncthreads();

    for (int kt = 0; kt < HIDDEN / 64; ++kt) {
        const int cur = kt & 1;
        // ---- issue next tile early (covered by compute below)
        if (kt < HIDDEN / 64 - 1) {
#pragma unroll
            for (int i = 0; i < 2; ++i) {
                const int row = i * 64 + wave * 8 + rowl;
                const float4* p = (const float4*)(Ab + (size_t)row * (HIDDEN * 4)
                                                  + (kt + 1) * 256 + (srcsw << 1));
                e0[i] = p[0]; e1[i] = p[1];
                GLOAD16(Bb + (size_t)row * (HIDDEN * 2) + (kt + 1) * 128 + srcsw,
                        Ls + BOFF + (cur ^ 1) * BBUF + i * 8192 + wave * 1024);
            }
        }
        // ---- compute tile k: A from single buffer, B from buf[cur]
        const char* Abase = Ls + AOFF;
        const char* Bbase = Ls + BOFF + cur * BBUF;
#pragma unroll
        for (int kc = 0; kc < 2; ++kc) {
            const int kbyte = kc * 64 + ((lane >> 4) << 4);
            bf16x8 af[4], bfr[2];
#pragma unroll
            for (int f2 = 0; f2 < 4; ++f2) {
                const int arow = wm * 64 + f2 * 16 + ql;
                af[f2] = *(const bf16x8*)(Abase + arow * 128 + (kbyte ^ ((arow & 7) << 4)));
            }
#pragma unroll
            for (int f2 = 0; f2 < 2; ++f2) {
                const int brow = wn * 32 + f2 * 16 + ql;
                bfr[f2] = *(const bf16x8*)(Bbase + brow * 128 + (kbyte ^ ((brow & 7) << 4)));
            }
#pragma unroll
            for (int mf = 0; mf < 4; ++mf)
#pragma unroll
                for (int nf = 0; nf < 2; ++nf)
                    acc[mf][nf] = __builtin_amdgcn_mfma_f32_16x16x32_bf16(af[mf], bfr[nf], acc[mf][nf], 0, 0, 0);
        }
        __syncthreads();   // all waves done reading A(k); B glds drained
        // ---- write A(k+1) into the single A buffer (regs already arrived)
        if (kt < HIDDEN / 64 - 1) {
            PROJ_CVT_WRITE_A(e0, e1)
            __syncthreads();   // lgkm-only: A writes visible before next compute
        }
    }
}

// EPI epilogue: bf16 out in per-head layout [(b*16+h)][s][d], seqlen 1<<slog
template <int NF>
__device__ __forceinline__ void epi_head(f32x4 (&acc)[4][NF], const float* bias,
                                         bf16_t* out, int m0, int n0, int slog,
                                         int wm, int wn, int lane)
{
#pragma unroll
    for (int mf = 0; mf < 4; ++mf) {
#pragma unroll
        for (int nf = 0; nf < NF; ++nf) {
            const int gn = n0 + wn * (NF * 16) + nf * 16 + (lane & 15);
            const float bv = bias[gn];
#pragma unroll
            for (int r = 0; r < 4; ++r) {
                const int gm = m0 + wm * 64 + mf * 16 + ((lane >> 4) << 2) + r;
                const float v = clamp50(acc[mf][nf][r] + bv);
                const int b = gm >> slog;
                const int s = gm & ((1 << slog) - 1);
                const int h = gn >> 6, d = gn & 63;
                out[((((size_t)(b * NHEADS + h)) << slog) + s) * HDIM + d] = (bf16_t)v;
            }
        }
    }
}

// ---------------------------------------------------------------------------
// MERGED projection GEMM v4, fused A-conversion. Grid 1280, 512 thr (8 waves).
// Bijective XCD swizzle lid = (bid&7)*160 + (bid>>3): 8 consecutive lids share
// an A m-panel on one XCD -> fp32 panel L2-resident after first fetch.
// ---------------------------------------------------------------------------
__global__ __launch_bounds__(512)
void gemm_proj_all(const float* __restrict__ qf32, const float* __restrict__ kvf32,
                   const bf16_t* __restrict__ w_bf,
                   const float* __restrict__ bq, const float* __restrict__ bk,
                   const float* __restrict__ bv,
                   bf16_t* __restrict__ qh, bf16_t* __restrict__ kh,
                   bf16_t* __restrict__ vt)
{
    __shared__ __align__(16) char Smem[49152];   // 48 KB: A 16K + B 2x16K

    const int bid = blockIdx.x;
    const int lid = (bid & 7) * 160 + (bid >> 3);

    int seg, j;
    if (lid < 256)      { seg = 0; j = lid; }
    else if (lid < 768) { seg = 1; j = lid - 256; }
    else                { seg = 2; j = lid - 768; }
    const int m0 = (j >> 3) * 128;
    const int n0 = (j & 7) * 128;
    const float*  A    = (seg == 0) ? qf32 : kvf32;
    const bf16_t* B    = w_bf + (size_t)seg * (HIDDEN * HIDDEN);   // Wq, Wk, Wv
    const float*  bias = (seg == 0) ? bq : (seg == 1) ? bk : bv;

    const int t = threadIdx.x;
    const int wave = t >> 6, lane = t & 63;
    const int wm = wave >> 2, wn = wave & 3;

    f32x4 acc[4][2] = {};
    proj_core4((const char*)A + (size_t)m0 * (HIDDEN * 4),
               (const char*)B + (size_t)n0 * (HIDDEN * 2),
               (char*)Smem, acc, wave, lane, wm, wn);

    if (seg == 0) {
        epi_head<2>(acc, bias, qh, m0, n0, 10, wm, wn, lane);
        return;
    }
    if (seg == 1) {
        epi_head<2>(acc, bias, kh, m0, n0, 11, wm, wn, lane);
        return;
    }

    // V: transpose epilogue via LDS (reuse Smem), 2 phases of 64 s-rows.
    bf16_t* Cls = (bf16_t*)Smem;         // [64][130]
    const int dl = t >> 2;               // 0..127
    const int sh = (t & 3) << 4;         // 0,16,32,48
    const int gn = n0 + dl;
    const int h = gn >> 6, d = gn & 63;
    const int bb = m0 >> 11;
    bf16_t* dst = vt + ((size_t)((bb * NHEADS + h) * HDIM + d)) * KVLEN
                + (m0 & (KVLEN - 1)) + sh;
    __syncthreads();
#pragma unroll
    for (int ph = 0; ph < 2; ++ph) {
        if (wm == ph) {
#pragma unroll
            for (int mf = 0; mf < 4; ++mf) {
#pragma unroll
                for (int nf = 0; nf < 2; ++nf) {
                    const int dcol = wn * 32 + nf * 16 + (lane & 15);
                    const float bv2 = bias[n0 + dcol];
#pragma unroll
                    for (int r = 0; r < 4; ++r) {
                        const int srow = mf * 16 + ((lane >> 4) << 2) + r;
                        Cls[srow * 130 + dcol] = (bf16_t)clamp50(acc[mf][nf][r] + bv2);
                    }
                }
            }
        }
        __syncthreads();
#pragma unroll
        for (int j0 = 0; j0 < 16; j0 += 8) {
            bf16x8 v;
#pragma unroll
            for (int jj = 0; jj < 8; ++jj) v[jj] = Cls[(sh + j0 + jj) * 130 + dl];
            *(bf16x8*)(dst + ph * 64 + j0) = v;
        }
        __syncthreads();
    }
}

// ---------------------------------------------------------------------------
// 8-WAVE all-bf16 GEMM core (output projection), 128xNT, dbuf glds.
// ---------------------------------------------------------------------------
template <int NT>
__device__ __forceinline__ void stage_tile8(const char* __restrict__ Ab,
                                            const char* __restrict__ Bb,
                                            char* base, int kt, int wave, int rowl, int srcsw)
{
#pragma unroll
    for (int i = 0; i < 2; ++i) {
        const int row = i * 64 + wave * 8 + rowl;
        GLOAD16(Ab + (size_t)row * (HIDDEN * 2) + kt * 128 + srcsw,
                base + i * 8192 + wave * 1024);
    }
#pragma unroll
    for (int i = 0; i < NT / 64; ++i) {
        const int row = i * 64 + wave * 8 + rowl;
        GLOAD16(Bb + (size_t)row * (HIDDEN * 2) + kt * 128 + srcsw,
                base + 16384 + i * 8192 + wave * 1024);
    }
}

template <int NT>
__device__ __forceinline__ void gemm_core_db8(const char* __restrict__ Ab,
                                              const char* __restrict__ Bb,
                                              char* Ls,
                                              f32x4 (&acc)[4][NT / 64],
                                              int wave, int lane, int wm, int wn)
{
    constexpr int NFB = NT / 64;
    constexpr int BUF = (128 + NT) * 128;
    const int srcsw = ((lane & 7) ^ (lane >> 3)) << 4;
    const int rowl = lane >> 3;
    const int ql = lane & 15;

    stage_tile8<NT>(Ab, Bb, Ls, 0, wave, rowl, srcsw);
    __syncthreads();

    for (int kt = 0; kt < HIDDEN / 64; ++kt) {
        const int cur = kt & 1;
        if (kt < HIDDEN / 64 - 1)
            stage_tile8<NT>(Ab, Bb, Ls + (cur ^ 1) * BUF, kt + 1, wave, rowl, srcsw);
        const char* Abase = Ls + cur * BUF;
        const char* Bbase = Abase + 16384;
#pragma unroll
        for (int kc = 0; kc < 2; ++kc) {
            const int kbyte = kc * 64 + ((lane >> 4) << 4);
            bf16x8 af[4], bfr[NFB];
#pragma unroll
            for (int f2 = 0; f2 < 4; ++f2) {
                const int arow = wm * 64 + f2 * 16 + ql;
                af[f2] = *(const bf16x8*)(Abase + arow * 128 + (kbyte ^ ((arow & 7) << 4)));
            }
#pragma unroll
            for (int f2 = 0; f2 < NFB; ++f2) {
                const int brow = wn * (NT / 4) + f2 * 16 + ql;
                bfr[f2] = *(const bf16x8*)(Bbase + brow * 128 + (kbyte ^ ((brow & 7) << 4)));
            }
#pragma unroll
            for (int mf = 0; mf < 4; ++mf)
#pragma unroll
                for (int nf = 0; nf < NFB; ++nf)
                    acc[mf][nf] = __builtin_amdgcn_mfma_f32_16x16x32_bf16(af[mf], bfr[nf], acc[mf][nf], 0, 0, 0);
        }
        __syncthreads();
    }
}

// ---------------------------------------------------------------------------
// Output-projection GEMM (fp32 out [M][1024]), 128x64 tiles, 8 waves,
// dbuf core, 1D grid 512 with panel-per-XCD swizzle.
// ---------------------------------------------------------------------------
__global__ __launch_bounds__(512)
void gemm_out_kernel(const bf16_t* __restrict__ A, const bf16_t* __restrict__ B,
                     const float* __restrict__ bias, float* __restrict__ out)
{
    constexpr int NT = 64;
    __shared__ __align__(16) bf16_t Smem[2 * (128 + NT) * 64];   // 48 KB

    const int bid = blockIdx.x;
    const int lid = (bid & 7) * 64 + (bid >> 3);   // 512 = 8 x 64, bijective
    const int m0 = (lid >> 4) * 128;
    const int n0 = (lid & 15) * NT;
    const int t = threadIdx.x;
    const int wave = t >> 6, lane = t & 63;
    const int wm = wave >> 2, wn = wave & 3;

    f32x4 acc[4][1] = {};
    gemm_core_db8<NT>((const char*)A + (size_t)m0 * (HIDDEN * 2),
                      (const char*)B + (size_t)n0 * (HIDDEN * 2),
                      (char*)Smem, acc, wave, lane, wm, wn);

#pragma unroll
    for (int mf = 0; mf < 4; ++mf) {
        const int gn = n0 + wn * 16 + (lane & 15);
        const float bv = bias[gn];
#pragma unroll
        for (int r = 0; r < 4; ++r) {
            const int gm = m0 + wm * 64 + mf * 16 + ((lane >> 4) << 2) + r;
            out[(size_t)gm * HIDDEN + gn] = clamp50(acc[mf][0][r] + bv);
        }
    }
}

// ---------------------------------------------------------------------------
// Flash attention v3: fixed-max softmax, swapped QK^T (P in registers),
// key-half split across wave pairs, 8 waves / 512 threads, XCD-grouped.
// ---------------------------------------------------------------------------
__global__ __launch_bounds__(512)
void attn_fwd_kernel(const bf16_t* __restrict__ Qh, const bf16_t* __restrict__ Kh,
                     const bf16_t* __restrict__ Vt, const float* __restrict__ maskadd,
                     bf16_t* __restrict__ aout)
{
    __shared__ __align__(16) bf16_t Kls[2][64 * 64];   // 16 KB
    __shared__ __align__(16) bf16_t Vls[2][64 * 64];   // 16 KB
    __shared__ __align__(16) float Cbuf[4][32 * 64];   // 32 KB combine
    __shared__ float Lbuf[4][2][16];

    const int f = blockIdx.x;
    const int o = (f & 7) * 64 + (f >> 3);
    const int qt = o & 7;
    const int bh = o >> 3;
    const int b = bh >> 4, h = bh & 15;
    const int t = threadIdx.x, wave = t >> 6, lane = t & 63;
    const int wq = wave & 3;
    const int wg = wave >> 2;
    const int g = lane >> 4, ql = lane & 15;

    const int qbase = qt * 128 + wq * 32;
    bf16x8 qf[2][2];
#pragma unroll
    for (int qq = 0; qq < 2; ++qq) {
        const bf16_t* qp = Qh + ((size_t)bh * QLEN + qbase + qq * 16 + ql) * HDIM + (g << 3);
        qf[qq][0] = *(const bf16x8*)qp;
        qf[qq][1] = *(const bf16x8*)(qp + 32);
    }

    f32x4 oacc[2][4] = {};
    float lsum[2] = {0.f, 0.f};

    const int srcsw = ((lane & 7) ^ (lane >> 3)) << 4;
    const int R = wave * 8 + (lane >> 3);
    const int kap = 32 * (R >> 5) + 8 * ((R >> 2) & 3) + 4 * ((R >> 4) & 1) + (R & 3);

    const char* Kb = (const char*)(Kh + (size_t)bh * KVLEN * HDIM);
    const char* Vb = (const char*)(Vt + (size_t)bh * HDIM * KVLEN);
    const float* mrow = maskadd + b * KVLEN + wg * 32 + g * 8;
    const int kb0 = g << 4;
    const int vcol = wg * 64 + kb0;

    GLOAD16(Kb + (size_t)kap * 128 + srcsw, (char*)&Kls[0][0] + wave * 1024);
    GLOAD16(Vb + (size_t)R * (KVLEN * 2) + srcsw, (char*)&Vls[0][0] + wave * 1024);
    f32x4 madd_c[2], madd_n[2];
    madd_c[0] = *(const f32x4*)(mrow);
    madd_c[1] = *(const f32x4*)(mrow + 4);
    __syncthreads();

    for (int kt = 0; kt < KVLEN / 64; ++kt) {
        const int cur = kt & 1;
        if (kt < KVLEN / 64 - 1) {
            const size_t ko = (size_t)(kt + 1) * 8192;
            GLOAD16(Kb + ko + (size_t)kap * 128 + srcsw,
                    (char*)&Kls[cur ^ 1][0] + wave * 1024);
            GLOAD16(Vb + (size_t)R * (KVLEN * 2) + (size_t)(kt + 1) * 128 + srcsw,
                    (char*)&Vls[cur ^ 1][0] + wave * 1024);
            madd_n[0] = *(const f32x4*)(mrow + (kt + 1) * 64);
            madd_n[1] = *(const f32x4*)(mrow + (kt + 1) * 64 + 4);
        }
        const char* Kc = (const char*)&Kls[cur][0];
        const char* Vc = (const char*)&Vls[cur][0];

        // ---- S^T = K Q^T over this wave's 32-key half
        f32x4 sacc[2][2] = {};
        __builtin_amdgcn_s_setprio(1);
#pragma unroll
        for (int kb = 0; kb < 2; ++kb) {
            const int key = wg * 32 + kb * 16 + ql;
            const int rowoff = key * 128;
            const int sw = (key & 7) << 4;
            const bf16x8 kf0 = *(const bf16x8*)(Kc + rowoff + ((kb0)      ^ sw));
            const bf16x8 kf1 = *(const bf16x8*)(Kc + rowoff + ((kb0 + 64) ^ sw));
#pragma unroll
            for (int qq = 0; qq < 2; ++qq) {
                sacc[qq][kb] = __builtin_amdgcn_mfma_f32_16x16x32_bf16(kf0, qf[qq][0], sacc[qq][kb], 0, 0, 0);
                sacc[qq][kb] = __builtin_amdgcn_mfma_f32_16x16x32_bf16(kf1, qf[qq][1], sacc[qq][kb], 0, 0, 0);
            }
        }
        __builtin_amdgcn_s_setprio(0);

        // ---- softmax weights in-register + pack to PV A-fragment
        bf16x8 pa[2];
#pragma unroll
        for (int qq = 0; qq < 2; ++qq) {
            float pv[2][4];
            float ls = 0.f;
#pragma unroll
            for (int kb = 0; kb < 2; ++kb) {
#pragma unroll
                for (int r = 0; r < 4; ++r) {
                    pv[kb][r] = __builtin_amdgcn_exp2f(
                        __builtin_fmaf(sacc[qq][kb][r], C_SCALE, madd_c[kb][r]));
                    ls += pv[kb][r];
                }
            }
            lsum[qq] += ls;
#pragma unroll
            for (int r = 0; r < 4; ++r) {
                pa[qq][r]     = (bf16_t)pv[0][r];
                pa[qq][4 + r] = (bf16_t)pv[1][r];
            }
        }

        // ---- O += P V over this key half
        __builtin_amdgcn_s_setprio(1);
#pragma unroll
        for (int db = 0; db < 4; ++db) {
            const int vrow = db * 16 + ql;
            const int vsw = (vrow & 7) << 4;
            const bf16x8 vf = *(const bf16x8*)(Vc + vrow * 128 + (vcol ^ vsw));
#pragma unroll
            for (int qq = 0; qq < 2; ++qq)
                oacc[qq][db] = __builtin_amdgcn_mfma_f32_16x16x32_bf16(pa[qq], vf, oacc[qq][db], 0, 0, 0);
        }
        __builtin_amdgcn_s_setprio(0);

        __syncthreads();
#pragma unroll
        for (int kb = 0; kb < 2; ++kb) madd_c[kb] = madd_n[kb];
    }

    // ---- combine key-halves: wg=1 publishes partials, wg=0 merges+stores
#pragma unroll
    for (int qq = 0; qq < 2; ++qq) {
        float l = lsum[qq];
        l += __shfl_xor(l, 16);
        l += __shfl_xor(l, 32);
        lsum[qq] = l;
    }
    const int rbase = g << 2;
    if (wg == 1) {
#pragma unroll
        for (int qq = 0; qq < 2; ++qq) {
#pragma unroll
            for (int db = 0; db < 4; ++db)
#pragma unroll
                for (int r = 0; r < 4; ++r)
                    Cbuf[wq][(qq * 16 + rbase + r) * 64 + db * 16 + ql] = oacc[qq][db][r];
            if (lane < 16) Lbuf[wq][qq][lane] = lsum[qq];
        }
    }
    __syncthreads();
    if (wg == 0) {
#pragma unroll
        for (int qq = 0; qq < 2; ++qq) {
            const float Lq = lsum[qq] + Lbuf[wq][qq][ql];
#pragma unroll
            for (int r = 0; r < 4; ++r) {
                const float Lr = __shfl(Lq, rbase + r);
                const float inv = 1.0f / Lr;
                const int qrow = qbase + qq * 16 + rbase + r;
                bf16_t* orow = aout + ((size_t)(b * QLEN + qrow)) * HIDDEN + h * HDIM;
#pragma unroll
                for (int db = 0; db < 4; ++db) {
                    const float add = Cbuf[wq][(qq * 16 + rbase + r) * 64 + db * 16 + ql];
                    orow[db * 16 + ql] = (bf16_t)((oacc[qq][db][r] + add) * inv);
                }
            }
        }
    }
}

// ---------------------------------------------------------------------------
extern "C" void kernel_launch(void* const* d_in, const int* in_sizes, int n_in,
                              void* d_out, int out_size, void* d_ws, size_t ws_size,
                              hipStream_t stream) {
    (void)in_sizes; (void)n_in; (void)out_size; (void)ws_size;
    const float* q   = (const float*)d_in[0];
    const float* kv  = (const float*)d_in[1];
    const void*  msk = d_in[2];
    const float* Wq  = (const float*)d_in[3];
    const float* bq  = (const float*)d_in[4];
    const float* Wk  = (const float*)d_in[5];
    const float* bk  = (const float*)d_in[6];
    const float* Wv  = (const float*)d_in[7];
    const float* bv  = (const float*)d_in[8];
    const float* Wo  = (const float*)d_in[9];
    const float* bo  = (const float*)d_in[10];

    char* ws = (char*)d_ws;
    const size_t MB = 1024 * 1024;
    float*  maskadd = (float*)ws;                              // 32 KB
    bf16_t* w_bf  = (bf16_t*)(ws + 32 * 1024);                 // 8 MB (4 weights)
    bf16_t* aout  = (bf16_t*)(ws + 32 * 1024 + 8  * MB);       // 8 MB
    bf16_t* qh    = (bf16_t*)(ws + 32 * 1024 + 32 * MB);       // 8 MB
    bf16_t* kh    = (bf16_t*)(ws + 32 * 1024 + 40 * MB);       // 16 MB
    bf16_t* vt    = (bf16_t*)(ws + 32 * 1024 + 56 * MB);       // 16 MB -> end 72 MB

    bf16_t* wo_bf = w_bf + (size_t)3 * HIDDEN * HIDDEN;

    cvt_w_mask_kernel<<<dim3(NWCVT + 4), 256, 0, stream>>>(
        Wq, Wk, Wv, Wo, w_bf, msk, maskadd);

    gemm_proj_all<<<dim3(1280), 512, 0, stream>>>(
        q, kv, w_bf, bq, bk, bv, qh, kh, vt);

    attn_fwd_kernel<<<dim3(512), 512, 0, stream>>>(qh, kh, vt, maskadd, aout);

    gemm_out_kernel<<<dim3(512), 512, 0, stream>>>(aout, wo_bf, bo, (float*)d_out);
}